// Round 1
// baseline (458.578 us; speedup 1.0000x reference)
//
#include <hip/hip_runtime.h>

#define B_ 2
#define T_ 2048
#define C_ 2048
#define NH_ 16
#define NKV_ 4
#define HD_ 128
#define M_ 4096          // B*T
#define NQKV_ 3072       // C + 2*NKV*HD

typedef __bf16 bf16x8 __attribute__((ext_vector_type(8)));
typedef float f32x4 __attribute__((ext_vector_type(4)));

__device__ __forceinline__ unsigned short f2bf(float f) {
  union { float f; unsigned u; } c{f};
  unsigned u = c.u + 0x7FFFu + ((c.u >> 16) & 1u);
  return (unsigned short)(u >> 16);
}
__device__ __forceinline__ float bf2f(unsigned short h) {
  union { unsigned u; float f; } c{(unsigned)h << 16};
  return c.f;
}

#define GLOAD_LDS16(g, l)                                        \
  __builtin_amdgcn_global_load_lds(                              \
      (const __attribute__((address_space(1))) void*)(g),        \
      (__attribute__((address_space(3))) void*)(l), 16, 0, 0)

// ---------------- RoPE cos/sin table: rt[t*64+i] = {cos,sin}(t * 10000^(-2i/128))
__global__ void rope_table_kernel(float2* __restrict__ rt) {
  int t = blockIdx.x, i = threadIdx.x;  // 2048 x 64
  float inv = powf(10000.f, -(float)(2 * i) / 128.f);
  float s, c;
  sincosf((float)t * inv, &s, &c);
  rt[t * 64 + i] = make_float2(c, s);
}

// ---------------- x f32 -> bf16 (vectorized)
__global__ void convx_kernel(const float* __restrict__ x, unsigned short* __restrict__ xb, int n4) {
  int i = blockIdx.x * blockDim.x + threadIdx.x;
  if (i >= n4) return;
  float4 v = reinterpret_cast<const float4*>(x)[i];
  union { ushort4 u; unsigned short s[4]; } o;
  o.s[0] = f2bf(v.x); o.s[1] = f2bf(v.y); o.s[2] = f2bf(v.z); o.s[3] = f2bf(v.w);
  reinterpret_cast<ushort4*>(xb)[i] = o.u;
}

// ---------------- W (K x N, f32 row-major) -> Wt (N x K, bf16)
__global__ void transpose_conv_kernel(const float* __restrict__ W, unsigned short* __restrict__ Wt,
                                      int K, int N) {
  __shared__ float tile[32][33];
  int bx = blockIdx.x * 32;  // n
  int by = blockIdx.y * 32;  // k
  int tx = threadIdx.x & 31, ty = threadIdx.x >> 5;  // 32x8
#pragma unroll
  for (int r = 0; r < 32; r += 8)
    tile[ty + r][tx] = W[(size_t)(by + ty + r) * N + bx + tx];
  __syncthreads();
#pragma unroll
  for (int r = 0; r < 32; r += 8)
    Wt[(size_t)(bx + ty + r) * K + by + tx] = f2bf(tile[tx][ty + r]);
}

// ---------------- RoPE applied in-place to q (cols 0..2047) and k (cols 2048..2559)
__global__ void rope_kernel(unsigned short* __restrict__ qkv, const float2* __restrict__ rt) {
  int g = blockIdx.x * blockDim.x + threadIdx.x;
  if (g >= M_ * 160) return;          // 160 octet-pairs per row: 128 q + 32 k
  int m = g / 160, u = g - m * 160;
  int t = m & (T_ - 1);
  int io, col0;
  if (u < 128) { io = (u & 7) * 8; col0 = (u >> 3) * HD_ + io; }
  else         { int uu = u - 128; io = (uu & 7) * 8; col0 = C_ + (uu >> 3) * HD_ + io; }
  unsigned short* p = qkv + (size_t)m * NQKV_ + col0;
  union V8 { uint4 v; unsigned short s[8]; };
  V8 a, b, oa, ob;
  a.v = *reinterpret_cast<const uint4*>(p);
  b.v = *reinterpret_cast<const uint4*>(p + 64);
#pragma unroll
  for (int j = 0; j < 8; ++j) {
    float2 cs = rt[t * 64 + io + j];
    float x1 = bf2f(a.s[j]), x2 = bf2f(b.s[j]);
    oa.s[j] = f2bf(x1 * cs.x - x2 * cs.y);
    ob.s[j] = f2bf(x2 * cs.x + x1 * cs.y);
  }
  *reinterpret_cast<uint4*>(p) = oa.v;
  *reinterpret_cast<uint4*>(p + 64) = ob.v;
}

// ---------------- V slice of qkv -> vt[(b*NKV+kvh)*HD + d][t]  (bf16 transpose)
__global__ void transpose_v_kernel(const unsigned short* __restrict__ qkv,
                                   unsigned short* __restrict__ vt) {
  __shared__ unsigned short tile[32][33];
  int bh = blockIdx.z;                 // b*NKV + kvh
  int b = bh >> 2, kvh = bh & 3;
  int t0 = blockIdx.x * 32, d0 = blockIdx.y * 32;
  int tx = threadIdx.x & 31, ty = threadIdx.x >> 5;
#pragma unroll
  for (int r = 0; r < 32; r += 8)
    tile[ty + r][tx] = qkv[(size_t)(b * T_ + t0 + ty + r) * NQKV_ + 2560 + kvh * HD_ + d0 + tx];
  __syncthreads();
#pragma unroll
  for (int r = 0; r < 32; r += 8)
    vt[(size_t)(bh * HD_ + d0 + ty + r) * T_ + t0 + tx] = tile[tx][ty + r];
}

// ---------------- bf16 GEMM: C(MxN) = A(MxK) * Bt(NxK)^T, 128x128 tile, BK=32
template <typename OUT>
__global__ __launch_bounds__(256) void gemm_bf16(const unsigned short* __restrict__ A,
                                                 const unsigned short* __restrict__ Bt,
                                                 OUT* __restrict__ Cm,
                                                 int M, int N, int K) {
  constexpr int BK = 32;
  __shared__ __align__(16) unsigned short Al[2][128 * BK];
  __shared__ __align__(16) unsigned short Bl[2][128 * BK];
  int tid = threadIdx.x, w = tid >> 6, lane = tid & 63;
  int l15 = lane & 15, l4 = lane >> 4;
  int wr = w >> 1, wc = w & 1;  // wave -> 64x64 quadrant
  size_t arow0 = (size_t)blockIdx.y * 128;
  size_t brow0 = (size_t)blockIdx.x * 128;

  f32x4 acc[4][4];
#pragma unroll
  for (int mi = 0; mi < 4; ++mi)
#pragma unroll
    for (int ni = 0; ni < 4; ++ni) acc[mi][ni] = (f32x4){0.f, 0.f, 0.f, 0.f};

  auto stage = [&](int buf, int k0) {
#pragma unroll
    for (int i = 0; i < 2; ++i) {                 // A tile: 8KB = 8 wave-insts
      int c = i * 256 + w * 64 + lane;            // chunk 0..511 (16B each)
      const unsigned short* g = A + (arow0 + (c >> 2)) * K + k0 + (c & 3) * 8;
      GLOAD_LDS16(g, &Al[buf][(i * 4 + w) * 512]);
    }
#pragma unroll
    for (int i = 0; i < 2; ++i) {
      int c = i * 256 + w * 64 + lane;
      const unsigned short* g = Bt + (brow0 + (c >> 2)) * K + k0 + (c & 3) * 8;
      GLOAD_LDS16(g, &Bl[buf][(i * 4 + w) * 512]);
    }
  };

  stage(0, 0);
  __syncthreads();
  int NT = K / BK, cur = 0;
  for (int kt = 0; kt < NT; ++kt) {
    if (kt + 1 < NT) stage(cur ^ 1, (kt + 1) * BK);
    const unsigned short* Ab = &Al[cur][0];
    const unsigned short* Bb = &Bl[cur][0];
    bf16x8 af[4], bfr[4];
#pragma unroll
    for (int mi = 0; mi < 4; ++mi)
      af[mi] = *reinterpret_cast<const bf16x8*>(Ab + (wr * 64 + mi * 16 + l15) * BK + l4 * 8);
#pragma unroll
    for (int ni = 0; ni < 4; ++ni)
      bfr[ni] = *reinterpret_cast<const bf16x8*>(Bb + (wc * 64 + ni * 16 + l15) * BK + l4 * 8);
#pragma unroll
    for (int mi = 0; mi < 4; ++mi)
#pragma unroll
      for (int ni = 0; ni < 4; ++ni)
        acc[mi][ni] = __builtin_amdgcn_mfma_f32_16x16x32_bf16(af[mi], bfr[ni], acc[mi][ni], 0, 0, 0);
    __syncthreads();
    cur ^= 1;
  }

#pragma unroll
  for (int mi = 0; mi < 4; ++mi)
#pragma unroll
    for (int ni = 0; ni < 4; ++ni) {
      size_t row = arow0 + wr * 64 + mi * 16 + l4 * 4;
      size_t col = brow0 + wc * 64 + ni * 16 + l15;
#pragma unroll
      for (int r = 0; r < 4; ++r) {
        float v = acc[mi][ni][r];
        if constexpr (sizeof(OUT) == 4) Cm[(row + r) * N + col] = v;
        else                            Cm[(row + r) * N + col] = f2bf(v);
      }
    }
}

// ---------------- flash attention: 4 waves x 32 q-rows, KVBLK=64, GQA
__global__ __launch_bounds__(256) void attn_kernel(const unsigned short* __restrict__ qkv,
                                                   const unsigned short* __restrict__ vt,
                                                   unsigned short* __restrict__ att) {
  constexpr int KB = 64;
  __shared__ __align__(16) unsigned short Kl[KB * 128];   // [kv][d] 16KB
  __shared__ __align__(16) unsigned short Vl[128 * KB];   // [d][kv] 16KB
  __shared__ __align__(16) unsigned short Pl[4][32 * KB]; // per-wave P, 16KB
  int tid = threadIdx.x, w = tid >> 6, lane = tid & 63;
  int l15 = lane & 15, l4 = lane >> 4;
  int q0 = blockIdx.x * 128;
  int bh = blockIdx.y, b = bh >> 4, h = bh & 15, kvh = h >> 2;
  const float scale = 0.08838834764831845f;  // 1/sqrt(128)

  // Q fragments in registers: wave rows q0+w*32 .. +31
  bf16x8 qf[2][4];
  {
    const unsigned short* qb = qkv + (size_t)(b * T_ + q0 + w * 32 + l15) * NQKV_ + h * HD_;
#pragma unroll
    for (int mi = 0; mi < 2; ++mi)
#pragma unroll
      for (int kk = 0; kk < 4; ++kk)
        qf[mi][kk] = *reinterpret_cast<const bf16x8*>(qb + (size_t)mi * 16 * NQKV_ + kk * 32 + l4 * 8);
  }

  f32x4 o[2][8];
  float mr[2][4], lr[2][4];
#pragma unroll
  for (int mi = 0; mi < 2; ++mi) {
#pragma unroll
    for (int di = 0; di < 8; ++di) o[mi][di] = (f32x4){0.f, 0.f, 0.f, 0.f};
#pragma unroll
    for (int r = 0; r < 4; ++r) { mr[mi][r] = -1e30f; lr[mi][r] = 0.f; }
  }

  int nt = q0 / KB + 2;  // causal: tiles up to q0+128
  for (int kt = 0; kt < nt; ++kt) {
    int kv0 = kt * KB;
#pragma unroll
    for (int i = 0; i < 4; ++i) {  // K tile 16KB
      int c = (i * 4 + w) * 64 + lane;
      const unsigned short* g =
          qkv + (size_t)(b * T_ + kv0 + (c >> 4)) * NQKV_ + C_ + kvh * HD_ + (c & 15) * 8;
      GLOAD_LDS16(g, Kl + (i * 4 + w) * 512);
    }
#pragma unroll
    for (int i = 0; i < 4; ++i) {  // V^T tile 16KB
      int c = (i * 4 + w) * 64 + lane;
      const unsigned short* g =
          vt + (size_t)((b * NKV_ + kvh) * HD_ + (c >> 3)) * T_ + kv0 + (c & 7) * 8;
      GLOAD_LDS16(g, Vl + (i * 4 + w) * 512);
    }
    __syncthreads();

    // S = Q K^T   (32 x 64 per wave)
    f32x4 s[2][4];
#pragma unroll
    for (int mi = 0; mi < 2; ++mi)
#pragma unroll
      for (int ni = 0; ni < 4; ++ni) s[mi][ni] = (f32x4){0.f, 0.f, 0.f, 0.f};
#pragma unroll
    for (int ni = 0; ni < 4; ++ni)
#pragma unroll
      for (int kk = 0; kk < 4; ++kk) {
        bf16x8 kf = *reinterpret_cast<const bf16x8*>(Kl + (ni * 16 + l15) * 128 + kk * 32 + l4 * 8);
#pragma unroll
        for (int mi = 0; mi < 2; ++mi)
          s[mi][ni] = __builtin_amdgcn_mfma_f32_16x16x32_bf16(qf[mi][kk], kf, s[mi][ni], 0, 0, 0);
      }

    // online softmax (rows live in 16-lane groups; reduce with shfl_xor 1/2/4/8)
#pragma unroll
    for (int mi = 0; mi < 2; ++mi) {
      float alpha[4];
#pragma unroll
      for (int r = 0; r < 4; ++r) {
        int qrow = q0 + w * 32 + mi * 16 + l4 * 4 + r;
        float rm = -1e30f;
#pragma unroll
        for (int ni = 0; ni < 4; ++ni) {
          float sv = s[mi][ni][r] * scale;
          int kcol = kv0 + ni * 16 + l15;
          sv = (kcol > qrow) ? -1e30f : sv;
          s[mi][ni][r] = sv;
          rm = fmaxf(rm, sv);
        }
#pragma unroll
        for (int msk = 1; msk < 16; msk <<= 1) rm = fmaxf(rm, __shfl_xor(rm, msk));
        float mold = mr[mi][r];
        float mnew = fmaxf(mold, rm);
        mr[mi][r] = mnew;
        alpha[r] = __expf(mold - mnew);
        float ps = 0.f;
#pragma unroll
        for (int ni = 0; ni < 4; ++ni) {
          float p = __expf(s[mi][ni][r] - mnew);
          s[mi][ni][r] = p;
          ps += p;
        }
#pragma unroll
        for (int msk = 1; msk < 16; msk <<= 1) ps += __shfl_xor(ps, msk);
        lr[mi][r] = alpha[r] * lr[mi][r] + ps;
      }
      f32x4 av = {alpha[0], alpha[1], alpha[2], alpha[3]};
#pragma unroll
      for (int di = 0; di < 8; ++di) o[mi][di] *= av;
#pragma unroll
      for (int ni = 0; ni < 4; ++ni)
#pragma unroll
        for (int r = 0; r < 4; ++r)
          Pl[w][(mi * 16 + l4 * 4 + r) * KB + ni * 16 + l15] = f2bf(s[mi][ni][r]);
    }

    // O += P V  (P from per-wave LDS, V^T from LDS)
#pragma unroll
    for (int kk = 0; kk < 2; ++kk) {
      bf16x8 pa[2];
#pragma unroll
      for (int mi = 0; mi < 2; ++mi)
        pa[mi] = *reinterpret_cast<const bf16x8*>(&Pl[w][(mi * 16 + l15) * KB + kk * 32 + l4 * 8]);
#pragma unroll
      for (int di = 0; di < 8; ++di) {
        bf16x8 vf = *reinterpret_cast<const bf16x8*>(Vl + (di * 16 + l15) * KB + kk * 32 + l4 * 8);
#pragma unroll
        for (int mi = 0; mi < 2; ++mi)
          o[mi][di] = __builtin_amdgcn_mfma_f32_16x16x32_bf16(pa[mi], vf, o[mi][di], 0, 0, 0);
      }
    }
    __syncthreads();
  }

#pragma unroll
  for (int mi = 0; mi < 2; ++mi)
#pragma unroll
    for (int r = 0; r < 4; ++r) {
      float inv = 1.f / lr[mi][r];
      size_t row = (size_t)(b * T_ + q0 + w * 32 + mi * 16 + l4 * 4 + r);
#pragma unroll
      for (int di = 0; di < 8; ++di)
        att[row * C_ + h * HD_ + di * 16 + l15] = f2bf(o[mi][di][r] * inv);
    }
}

extern "C" void kernel_launch(void* const* d_in, const int* in_sizes, int n_in,
                              void* d_out, int out_size, void* d_ws, size_t ws_size,
                              hipStream_t stream) {
  const float* x  = (const float*)d_in[0];
  const float* Wq = (const float*)d_in[1];
  const float* Wk = (const float*)d_in[2];
  const float* Wv = (const float*)d_in[3];
  const float* Wp = (const float*)d_in[4];
  float* out = (float*)d_out;
  char* ws = (char*)d_ws;

  // workspace layout (bytes); total 68,157,440
  unsigned short* xb  = (unsigned short*)(ws);              // 4096x2048 bf16 (reused as att)
  unsigned short* wt  = (unsigned short*)(ws + 16777216);   // 5120x2048 bf16 (Wq^T|Wk^T|Wv^T|Wp^T)
  unsigned short* qkv = (unsigned short*)(ws + 37748736);   // 4096x3072 bf16
  float2*         rt  = (float2*)(ws + 62914560);           // 2048x64 {cos,sin}
  unsigned short* vt  = (unsigned short*)(ws + 63963136);   // 8x128x2048 bf16
  unsigned short* att = xb;                                 // alias: xb dead after GEMM1

  rope_table_kernel<<<T_, 64, 0, stream>>>(rt);
  convx_kernel<<<(M_ * C_ / 4 + 255) / 256, 256, 0, stream>>>(x, xb, M_ * C_ / 4);
  transpose_conv_kernel<<<dim3(64, 64), 256, 0, stream>>>(Wq, wt, C_, C_);
  transpose_conv_kernel<<<dim3(16, 64), 256, 0, stream>>>(Wk, wt + (size_t)2048 * 2048, C_, 512);
  transpose_conv_kernel<<<dim3(16, 64), 256, 0, stream>>>(Wv, wt + (size_t)2560 * 2048, C_, 512);
  transpose_conv_kernel<<<dim3(64, 64), 256, 0, stream>>>(Wp, wt + (size_t)3072 * 2048, C_, 2048);

  gemm_bf16<unsigned short><<<dim3(NQKV_ / 128, M_ / 128), 256, 0, stream>>>(
      xb, wt, qkv, M_, NQKV_, C_);
  rope_kernel<<<(M_ * 160 + 255) / 256, 256, 0, stream>>>(qkv, rt);
  transpose_v_kernel<<<dim3(T_ / 32, HD_ / 32, B_ * NKV_), 256, 0, stream>>>(qkv, vt);
  attn_kernel<<<dim3(T_ / 128, B_ * NH_), 256, 0, stream>>>(qkv, vt, att);
  gemm_bf16<float><<<dim3(C_ / 128, M_ / 128), 256, 0, stream>>>(
      att, wt + (size_t)3072 * 2048, out, M_, C_, C_);
}

// Round 2
// 450.762 us; speedup vs baseline: 1.0173x; 1.0173x over previous
//
#include <hip/hip_runtime.h>

#define B_ 2
#define T_ 2048
#define C_ 2048
#define NH_ 16
#define NKV_ 4
#define HD_ 128
#define M_ 4096          // B*T
#define NQKV_ 3072       // C + 2*NKV*HD

typedef __bf16 bf16x8 __attribute__((ext_vector_type(8)));
typedef float f32x4 __attribute__((ext_vector_type(4)));

__device__ __forceinline__ unsigned short f2bf(float f) {
  union { float f; unsigned u; } c{f};
  unsigned u = c.u + 0x7FFFu + ((c.u >> 16) & 1u);
  return (unsigned short)(u >> 16);
}
__device__ __forceinline__ float bf2f(unsigned short h) {
  union { unsigned u; float f; } c{(unsigned)h << 16};
  return c.f;
}

#define GLOAD_LDS16(g, l)                                        \
  __builtin_amdgcn_global_load_lds(                              \
      (const __attribute__((address_space(1))) void*)(g),        \
      (__attribute__((address_space(3))) void*)(l), 16, 0, 0)

// ---------------- RoPE cos/sin table: rt[t*64+i] = {cos,sin}(t * 10000^(-2i/128))
__global__ void rope_table_kernel(float2* __restrict__ rt) {
  int t = blockIdx.x, i = threadIdx.x;  // 2048 x 64
  float inv = powf(10000.f, -(float)(2 * i) / 128.f);
  float s, c;
  sincosf((float)t * inv, &s, &c);
  rt[t * 64 + i] = make_float2(c, s);
}

// ---------------- x f32 -> bf16 (vectorized)
__global__ void convx_kernel(const float* __restrict__ x, unsigned short* __restrict__ xb, int n4) {
  int i = blockIdx.x * blockDim.x + threadIdx.x;
  if (i >= n4) return;
  float4 v = reinterpret_cast<const float4*>(x)[i];
  union { ushort4 u; unsigned short s[4]; } o;
  o.s[0] = f2bf(v.x); o.s[1] = f2bf(v.y); o.s[2] = f2bf(v.z); o.s[3] = f2bf(v.w);
  reinterpret_cast<ushort4*>(xb)[i] = o.u;
}

// ---------------- W (K x N, f32 row-major) -> Wt (N x K, bf16)
__global__ void transpose_conv_kernel(const float* __restrict__ W, unsigned short* __restrict__ Wt,
                                      int K, int N) {
  __shared__ float tile[32][33];
  int bx = blockIdx.x * 32;  // n
  int by = blockIdx.y * 32;  // k
  int tx = threadIdx.x & 31, ty = threadIdx.x >> 5;  // 32x8
#pragma unroll
  for (int r = 0; r < 32; r += 8)
    tile[ty + r][tx] = W[(size_t)(by + ty + r) * N + bx + tx];
  __syncthreads();
#pragma unroll
  for (int r = 0; r < 32; r += 8)
    Wt[(size_t)(bx + ty + r) * K + by + tx] = f2bf(tile[tx][ty + r]);
}

// ---------------- RoPE applied in-place to q (cols 0..2047) and k (cols 2048..2559)
__global__ void rope_kernel(unsigned short* __restrict__ qkv, const float2* __restrict__ rt) {
  int g = blockIdx.x * blockDim.x + threadIdx.x;
  if (g >= M_ * 160) return;          // 160 octet-pairs per row: 128 q + 32 k
  int m = g / 160, u = g - m * 160;
  int t = m & (T_ - 1);
  int io, col0;
  if (u < 128) { io = (u & 7) * 8; col0 = (u >> 3) * HD_ + io; }
  else         { int uu = u - 128; io = (uu & 7) * 8; col0 = C_ + (uu >> 3) * HD_ + io; }
  unsigned short* p = qkv + (size_t)m * NQKV_ + col0;
  union V8 { uint4 v; unsigned short s[8]; };
  V8 a, b, oa, ob;
  a.v = *reinterpret_cast<const uint4*>(p);
  b.v = *reinterpret_cast<const uint4*>(p + 64);
#pragma unroll
  for (int j = 0; j < 8; ++j) {
    float2 cs = rt[t * 64 + io + j];
    float x1 = bf2f(a.s[j]), x2 = bf2f(b.s[j]);
    oa.s[j] = f2bf(x1 * cs.x - x2 * cs.y);
    ob.s[j] = f2bf(x2 * cs.x + x1 * cs.y);
  }
  *reinterpret_cast<uint4*>(p) = oa.v;
  *reinterpret_cast<uint4*>(p + 64) = ob.v;
}

// ---------------- V slice of qkv -> vt[(b*NKV+kvh)*HD + d][t]  (bf16 transpose)
__global__ void transpose_v_kernel(const unsigned short* __restrict__ qkv,
                                   unsigned short* __restrict__ vt) {
  __shared__ unsigned short tile[32][33];
  int bh = blockIdx.z;                 // b*NKV + kvh
  int b = bh >> 2, kvh = bh & 3;
  int t0 = blockIdx.x * 32, d0 = blockIdx.y * 32;
  int tx = threadIdx.x & 31, ty = threadIdx.x >> 5;
#pragma unroll
  for (int r = 0; r < 32; r += 8)
    tile[ty + r][tx] = qkv[(size_t)(b * T_ + t0 + ty + r) * NQKV_ + 2560 + kvh * HD_ + d0 + tx];
  __syncthreads();
#pragma unroll
  for (int r = 0; r < 32; r += 8)
    vt[(size_t)(bh * HD_ + d0 + ty + r) * T_ + t0 + tx] = tile[tx][ty + r];
}

// ---------------- bf16 GEMM: C(MxN) = A(MxK) * Bt(NxK)^T, 128x128 tile, BK=32
template <typename OUT>
__global__ __launch_bounds__(256) void gemm_bf16(const unsigned short* __restrict__ A,
                                                 const unsigned short* __restrict__ Bt,
                                                 OUT* __restrict__ Cm,
                                                 int M, int N, int K) {
  constexpr int BK = 32;
  __shared__ __align__(16) unsigned short Al[2][128 * BK];
  __shared__ __align__(16) unsigned short Bl[2][128 * BK];
  int tid = threadIdx.x, w = tid >> 6, lane = tid & 63;
  int l15 = lane & 15, l4 = lane >> 4;
  int wr = w >> 1, wc = w & 1;  // wave -> 64x64 quadrant
  size_t arow0 = (size_t)blockIdx.y * 128;
  size_t brow0 = (size_t)blockIdx.x * 128;

  f32x4 acc[4][4];
#pragma unroll
  for (int mi = 0; mi < 4; ++mi)
#pragma unroll
    for (int ni = 0; ni < 4; ++ni) acc[mi][ni] = (f32x4){0.f, 0.f, 0.f, 0.f};

  auto stage = [&](int buf, int k0) {
#pragma unroll
    for (int i = 0; i < 2; ++i) {                 // A tile: 8KB = 8 wave-insts
      int c = i * 256 + w * 64 + lane;            // chunk 0..511 (16B each)
      const unsigned short* g = A + (arow0 + (c >> 2)) * K + k0 + (c & 3) * 8;
      GLOAD_LDS16(g, &Al[buf][(i * 4 + w) * 512]);
    }
#pragma unroll
    for (int i = 0; i < 2; ++i) {
      int c = i * 256 + w * 64 + lane;
      const unsigned short* g = Bt + (brow0 + (c >> 2)) * K + k0 + (c & 3) * 8;
      GLOAD_LDS16(g, &Bl[buf][(i * 4 + w) * 512]);
    }
  };

  stage(0, 0);
  __syncthreads();
  int NT = K / BK, cur = 0;
  for (int kt = 0; kt < NT; ++kt) {
    if (kt + 1 < NT) stage(cur ^ 1, (kt + 1) * BK);
    const unsigned short* Ab = &Al[cur][0];
    const unsigned short* Bb = &Bl[cur][0];
    bf16x8 af[4], bfr[4];
#pragma unroll
    for (int mi = 0; mi < 4; ++mi)
      af[mi] = *reinterpret_cast<const bf16x8*>(Ab + (wr * 64 + mi * 16 + l15) * BK + l4 * 8);
#pragma unroll
    for (int ni = 0; ni < 4; ++ni)
      bfr[ni] = *reinterpret_cast<const bf16x8*>(Bb + (wc * 64 + ni * 16 + l15) * BK + l4 * 8);
#pragma unroll
    for (int mi = 0; mi < 4; ++mi)
#pragma unroll
      for (int ni = 0; ni < 4; ++ni)
        acc[mi][ni] = __builtin_amdgcn_mfma_f32_16x16x32_bf16(af[mi], bfr[ni], acc[mi][ni], 0, 0, 0);
    __syncthreads();
    cur ^= 1;
  }

#pragma unroll
  for (int mi = 0; mi < 4; ++mi)
#pragma unroll
    for (int ni = 0; ni < 4; ++ni) {
      size_t row = arow0 + wr * 64 + mi * 16 + l4 * 4;
      size_t col = brow0 + wc * 64 + ni * 16 + l15;
#pragma unroll
      for (int r = 0; r < 4; ++r) {
        float v = acc[mi][ni][r];
        if constexpr (sizeof(OUT) == 4) Cm[(row + r) * N + col] = v;
        else                            Cm[(row + r) * N + col] = f2bf(v);
      }
    }
}

// ---------------- flash attention: 4 waves x 16 q-rows each (QBLK=64), KVBLK=64, GQA
// K/V/P LDS tiles XOR-swizzled (16B-chunk ^= row&7); K/V staged via global_load_lds
// with pre-swizzled per-lane global source (linear LDS dest).
__global__ __launch_bounds__(256, 4) void attn_kernel(const unsigned short* __restrict__ qkv,
                                                      const unsigned short* __restrict__ vt,
                                                      unsigned short* __restrict__ att) {
  constexpr int KB = 64;
  __shared__ __align__(16) unsigned short Kl[KB * 128];    // [kv][d]  16KB, swizzled
  __shared__ __align__(16) unsigned short Vl[128 * KB];    // [d][kv]  16KB, swizzled
  __shared__ __align__(16) unsigned short Pl[4][16 * KB];  // per-wave P, 8KB, swizzled
  int tid = threadIdx.x, w = tid >> 6, lane = tid & 63;
  int l15 = lane & 15, l4 = lane >> 4;
  int q0 = blockIdx.x * 64;
  int bh = blockIdx.y, b = bh >> 4, h = bh & 15, kvh = h >> 2;
  int qr0 = q0 + w * 16;  // this wave's first q row

  // Q fragments in registers, pre-scaled by 1/sqrt(HD)
  bf16x8 qf[4];
  {
    const unsigned short* qb = qkv + (size_t)(b * T_ + qr0 + l15) * NQKV_ + h * HD_;
    const float scale = 0.08838834764831845f;
#pragma unroll
    for (int kk = 0; kk < 4; ++kk) {
      bf16x8 t = *reinterpret_cast<const bf16x8*>(qb + kk * 32 + l4 * 8);
#pragma unroll
      for (int j = 0; j < 8; ++j) t[j] = (__bf16)((float)t[j] * scale);
      qf[kk] = t;
    }
  }

  f32x4 o[8];
  float mr[4], lr[4];
#pragma unroll
  for (int di = 0; di < 8; ++di) o[di] = (f32x4){0.f, 0.f, 0.f, 0.f};
#pragma unroll
  for (int r = 0; r < 4; ++r) { mr[r] = -1e30f; lr[r] = 0.f; }

  int nt = q0 / KB + 1;  // causal
  for (int kt = 0; kt < nt; ++kt) {
    int kv0 = kt * KB;
#pragma unroll
    for (int i = 0; i < 4; ++i) {  // K tile: chunk c ^= (row&7), row = c>>4
      int c = (i * 4 + w) * 64 + lane;
      int g = c ^ ((c >> 4) & 7);
      const unsigned short* src =
          qkv + (size_t)(b * T_ + kv0 + (g >> 4)) * NQKV_ + C_ + kvh * HD_ + (g & 15) * 8;
      GLOAD_LDS16(src, Kl + (i * 4 + w) * 512);
    }
#pragma unroll
    for (int i = 0; i < 4; ++i) {  // V^T tile: chunk c ^= (row&7), row = c>>3
      int c = (i * 4 + w) * 64 + lane;
      int g = c ^ ((c >> 3) & 7);
      const unsigned short* src =
          vt + (size_t)((b * NKV_ + kvh) * HD_ + (g >> 3)) * T_ + kv0 + (g & 7) * 8;
      GLOAD_LDS16(src, Vl + (i * 4 + w) * 512);
    }
    __syncthreads();

    // S = Q K^T   (16 x 64 per wave)
    f32x4 s[4];
#pragma unroll
    for (int ni = 0; ni < 4; ++ni) s[ni] = (f32x4){0.f, 0.f, 0.f, 0.f};
#pragma unroll
    for (int ni = 0; ni < 4; ++ni)
#pragma unroll
      for (int kk = 0; kk < 4; ++kk) {
        bf16x8 kf = *reinterpret_cast<const bf16x8*>(
            Kl + (((ni * 16 + l15) * 128 + kk * 32 + l4 * 8) ^ ((l15 & 7) << 3)));
        s[ni] = __builtin_amdgcn_mfma_f32_16x16x32_bf16(qf[kk], kf, s[ni], 0, 0, 0);
      }

    // online softmax (rows live across 16 lanes; reduce with shfl_xor 1/2/4/8)
    bool need_mask = (kv0 + KB - 1) > qr0;
    float alpha[4];
#pragma unroll
    for (int r = 0; r < 4; ++r) {
      int qrow = qr0 + l4 * 4 + r;
      float rm = -1e30f;
#pragma unroll
      for (int ni = 0; ni < 4; ++ni) {
        float sv = s[ni][r];
        if (need_mask && (kv0 + ni * 16 + l15 > qrow)) sv = -1e30f;
        s[ni][r] = sv;
        rm = fmaxf(rm, sv);
      }
#pragma unroll
      for (int msk = 1; msk < 16; msk <<= 1) rm = fmaxf(rm, __shfl_xor(rm, msk));
      float mold = mr[r];
      float mnew = fmaxf(mold, rm);
      mr[r] = mnew;
      alpha[r] = __expf(mold - mnew);
      float ps = 0.f;
#pragma unroll
      for (int ni = 0; ni < 4; ++ni) {
        float p = __expf(s[ni][r] - mnew);
        s[ni][r] = p;
        ps += p;
      }
#pragma unroll
      for (int msk = 1; msk < 16; msk <<= 1) ps += __shfl_xor(ps, msk);
      lr[r] = alpha[r] * lr[r] + ps;
    }
    f32x4 av = {alpha[0], alpha[1], alpha[2], alpha[3]};
#pragma unroll
    for (int di = 0; di < 8; ++di) o[di] *= av;
#pragma unroll
    for (int ni = 0; ni < 4; ++ni)
#pragma unroll
      for (int r = 0; r < 4; ++r) {
        int row = l4 * 4 + r;
        Pl[w][((row * KB) + ni * 16 + l15) ^ ((row & 7) << 3)] = f2bf(s[ni][r]);
      }

    // O += P V  (P from per-wave swizzled LDS, V^T from swizzled LDS)
#pragma unroll
    for (int kk = 0; kk < 2; ++kk) {
      bf16x8 pa = *reinterpret_cast<const bf16x8*>(
          &Pl[w][(l15 * KB + kk * 32 + l4 * 8) ^ ((l15 & 7) << 3)]);
#pragma unroll
      for (int di = 0; di < 8; ++di) {
        bf16x8 vf = *reinterpret_cast<const bf16x8*>(
            Vl + (((di * 16 + l15) * KB + kk * 32 + l4 * 8) ^ ((l15 & 7) << 3)));
        o[di] = __builtin_amdgcn_mfma_f32_16x16x32_bf16(pa, vf, o[di], 0, 0, 0);
      }
    }
    __syncthreads();
  }

#pragma unroll
  for (int r = 0; r < 4; ++r) {
    float inv = 1.f / lr[r];
    size_t row = (size_t)(b * T_ + qr0 + l4 * 4 + r);
#pragma unroll
    for (int di = 0; di < 8; ++di)
      att[row * C_ + h * HD_ + di * 16 + l15] = f2bf(o[di][r] * inv);
  }
}

extern "C" void kernel_launch(void* const* d_in, const int* in_sizes, int n_in,
                              void* d_out, int out_size, void* d_ws, size_t ws_size,
                              hipStream_t stream) {
  const float* x  = (const float*)d_in[0];
  const float* Wq = (const float*)d_in[1];
  const float* Wk = (const float*)d_in[2];
  const float* Wv = (const float*)d_in[3];
  const float* Wp = (const float*)d_in[4];
  float* out = (float*)d_out;
  char* ws = (char*)d_ws;

  // workspace layout (bytes); total 68,157,440
  unsigned short* xb  = (unsigned short*)(ws);              // 4096x2048 bf16 (reused as att)
  unsigned short* wt  = (unsigned short*)(ws + 16777216);   // 5120x2048 bf16 (Wq^T|Wk^T|Wv^T|Wp^T)
  unsigned short* qkv = (unsigned short*)(ws + 37748736);   // 4096x3072 bf16
  float2*         rt  = (float2*)(ws + 62914560);           // 2048x64 {cos,sin}
  unsigned short* vt  = (unsigned short*)(ws + 63963136);   // 8x128x2048 bf16
  unsigned short* att = xb;                                 // alias: xb dead after GEMM1

  rope_table_kernel<<<T_, 64, 0, stream>>>(rt);
  convx_kernel<<<(M_ * C_ / 4 + 255) / 256, 256, 0, stream>>>(x, xb, M_ * C_ / 4);
  transpose_conv_kernel<<<dim3(64, 64), 256, 0, stream>>>(Wq, wt, C_, C_);
  transpose_conv_kernel<<<dim3(16, 64), 256, 0, stream>>>(Wk, wt + (size_t)2048 * 2048, C_, 512);
  transpose_conv_kernel<<<dim3(16, 64), 256, 0, stream>>>(Wv, wt + (size_t)2560 * 2048, C_, 512);
  transpose_conv_kernel<<<dim3(64, 64), 256, 0, stream>>>(Wp, wt + (size_t)3072 * 2048, C_, 2048);

  gemm_bf16<unsigned short><<<dim3(NQKV_ / 128, M_ / 128), 256, 0, stream>>>(
      xb, wt, qkv, M_, NQKV_, C_);
  rope_kernel<<<(M_ * 160 + 255) / 256, 256, 0, stream>>>(qkv, rt);
  transpose_v_kernel<<<dim3(T_ / 32, HD_ / 32, B_ * NKV_), 256, 0, stream>>>(qkv, vt);
  attn_kernel<<<dim3(T_ / 64, B_ * NH_), 256, 0, stream>>>(qkv, vt, att);
  gemm_bf16<float><<<dim3(C_ / 128, M_ / 128), 256, 0, stream>>>(
      att, wt + (size_t)3072 * 2048, out, M_, C_, C_);
}

// Round 3
// 336.911 us; speedup vs baseline: 1.3611x; 1.3379x over previous
//
#include <hip/hip_runtime.h>

#define B_ 2
#define T_ 2048
#define C_ 2048
#define NH_ 16
#define NKV_ 4
#define HD_ 128
#define M_ 4096          // B*T
#define NQKV_ 3072       // C + 2*NKV*HD

typedef __bf16 bf16x8 __attribute__((ext_vector_type(8)));
typedef float f32x4 __attribute__((ext_vector_type(4)));

__device__ __forceinline__ unsigned short f2bf(float f) {
  union { float f; unsigned u; } c{f};
  unsigned u = c.u + 0x7FFFu + ((c.u >> 16) & 1u);
  return (unsigned short)(u >> 16);
}
__device__ __forceinline__ float bf2f(unsigned short h) {
  union { unsigned u; float f; } c{(unsigned)h << 16};
  return c.f;
}

#define GLOAD_LDS16(g, l)                                        \
  __builtin_amdgcn_global_load_lds(                              \
      (const __attribute__((address_space(1))) void*)(g),        \
      (__attribute__((address_space(3))) void*)(l), 16, 0, 0)

// ---------------- RoPE cos/sin table: rt[t*64+i] = {cos,sin}(t * 10000^(-2i/128))
__global__ void rope_table_kernel(float2* __restrict__ rt) {
  int t = blockIdx.x, i = threadIdx.x;  // 2048 x 64
  float inv = powf(10000.f, -(float)(2 * i) / 128.f);
  float s, c;
  sincosf((float)t * inv, &s, &c);
  rt[t * 64 + i] = make_float2(c, s);
}

// ---------------- x f32 -> bf16 (vectorized)
__global__ void convx_kernel(const float* __restrict__ x, unsigned short* __restrict__ xb, int n4) {
  int i = blockIdx.x * blockDim.x + threadIdx.x;
  if (i >= n4) return;
  float4 v = reinterpret_cast<const float4*>(x)[i];
  union { ushort4 u; unsigned short s[4]; } o;
  o.s[0] = f2bf(v.x); o.s[1] = f2bf(v.y); o.s[2] = f2bf(v.z); o.s[3] = f2bf(v.w);
  reinterpret_cast<ushort4*>(xb)[i] = o.u;
}

// ---------------- W (K x N, f32 row-major) -> Wt (N x K, bf16)
__global__ void transpose_conv_kernel(const float* __restrict__ W, unsigned short* __restrict__ Wt,
                                      int K, int N) {
  __shared__ float tile[32][33];
  int bx = blockIdx.x * 32;  // n
  int by = blockIdx.y * 32;  // k
  int tx = threadIdx.x & 31, ty = threadIdx.x >> 5;  // 32x8
#pragma unroll
  for (int r = 0; r < 32; r += 8)
    tile[ty + r][tx] = W[(size_t)(by + ty + r) * N + bx + tx];
  __syncthreads();
#pragma unroll
  for (int r = 0; r < 32; r += 8)
    Wt[(size_t)(bx + ty + r) * K + by + tx] = f2bf(tile[tx][ty + r]);
}

// ---------------- RoPE applied in-place to q (cols 0..2047) and k (cols 2048..2559)
__global__ void rope_kernel(unsigned short* __restrict__ qkv, const float2* __restrict__ rt) {
  int g = blockIdx.x * blockDim.x + threadIdx.x;
  if (g >= M_ * 160) return;          // 160 octet-pairs per row: 128 q + 32 k
  int m = g / 160, u = g - m * 160;
  int t = m & (T_ - 1);
  int io, col0;
  if (u < 128) { io = (u & 7) * 8; col0 = (u >> 3) * HD_ + io; }
  else         { int uu = u - 128; io = (uu & 7) * 8; col0 = C_ + (uu >> 3) * HD_ + io; }
  unsigned short* p = qkv + (size_t)m * NQKV_ + col0;
  union V8 { uint4 v; unsigned short s[8]; };
  V8 a, b, oa, ob;
  a.v = *reinterpret_cast<const uint4*>(p);
  b.v = *reinterpret_cast<const uint4*>(p + 64);
#pragma unroll
  for (int j = 0; j < 8; ++j) {
    float2 cs = rt[t * 64 + io + j];
    float x1 = bf2f(a.s[j]), x2 = bf2f(b.s[j]);
    oa.s[j] = f2bf(x1 * cs.x - x2 * cs.y);
    ob.s[j] = f2bf(x2 * cs.x + x1 * cs.y);
  }
  *reinterpret_cast<uint4*>(p) = oa.v;
  *reinterpret_cast<uint4*>(p + 64) = ob.v;
}

// ---------------- V slice of qkv -> vt[(b*NKV+kvh)*HD + d][t]  (bf16 transpose)
__global__ void transpose_v_kernel(const unsigned short* __restrict__ qkv,
                                   unsigned short* __restrict__ vt) {
  __shared__ unsigned short tile[32][33];
  int bh = blockIdx.z;                 // b*NKV + kvh
  int b = bh >> 2, kvh = bh & 3;
  int t0 = blockIdx.x * 32, d0 = blockIdx.y * 32;
  int tx = threadIdx.x & 31, ty = threadIdx.x >> 5;
#pragma unroll
  for (int r = 0; r < 32; r += 8)
    tile[ty + r][tx] = qkv[(size_t)(b * T_ + t0 + ty + r) * NQKV_ + 2560 + kvh * HD_ + d0 + tx];
  __syncthreads();
#pragma unroll
  for (int r = 0; r < 32; r += 8)
    vt[(size_t)(bh * HD_ + d0 + ty + r) * T_ + t0 + tx] = tile[tx][ty + r];
}

// ---------------- bf16 GEMM: C(MxN) = A(MxK) * Bt(NxK)^T, 128x128 tile, BK=32
template <typename OUT>
__global__ __launch_bounds__(256) void gemm_bf16(const unsigned short* __restrict__ A,
                                                 const unsigned short* __restrict__ Bt,
                                                 OUT* __restrict__ Cm,
                                                 int M, int N, int K) {
  constexpr int BK = 32;
  __shared__ __align__(16) unsigned short Al[2][128 * BK];
  __shared__ __align__(16) unsigned short Bl[2][128 * BK];
  int tid = threadIdx.x, w = tid >> 6, lane = tid & 63;
  int l15 = lane & 15, l4 = lane >> 4;
  int wr = w >> 1, wc = w & 1;  // wave -> 64x64 quadrant
  size_t arow0 = (size_t)blockIdx.y * 128;
  size_t brow0 = (size_t)blockIdx.x * 128;

  f32x4 acc[4][4];
#pragma unroll
  for (int mi = 0; mi < 4; ++mi)
#pragma unroll
    for (int ni = 0; ni < 4; ++ni) acc[mi][ni] = (f32x4){0.f, 0.f, 0.f, 0.f};

  auto stage = [&](int buf, int k0) {
#pragma unroll
    for (int i = 0; i < 2; ++i) {                 // A tile: 8KB = 8 wave-insts
      int c = i * 256 + w * 64 + lane;            // chunk 0..511 (16B each)
      const unsigned short* g = A + (arow0 + (c >> 2)) * K + k0 + (c & 3) * 8;
      GLOAD_LDS16(g, &Al[buf][(i * 4 + w) * 512]);
    }
#pragma unroll
    for (int i = 0; i < 2; ++i) {
      int c = i * 256 + w * 64 + lane;
      const unsigned short* g = Bt + (brow0 + (c >> 2)) * K + k0 + (c & 3) * 8;
      GLOAD_LDS16(g, &Bl[buf][(i * 4 + w) * 512]);
    }
  };

  stage(0, 0);
  __syncthreads();
  int NT = K / BK, cur = 0;
  for (int kt = 0; kt < NT; ++kt) {
    if (kt + 1 < NT) stage(cur ^ 1, (kt + 1) * BK);
    const unsigned short* Ab = &Al[cur][0];
    const unsigned short* Bb = &Bl[cur][0];
    bf16x8 af[4], bfr[4];
#pragma unroll
    for (int mi = 0; mi < 4; ++mi)
      af[mi] = *reinterpret_cast<const bf16x8*>(Ab + (wr * 64 + mi * 16 + l15) * BK + l4 * 8);
#pragma unroll
    for (int ni = 0; ni < 4; ++ni)
      bfr[ni] = *reinterpret_cast<const bf16x8*>(Bb + (wc * 64 + ni * 16 + l15) * BK + l4 * 8);
#pragma unroll
    for (int mi = 0; mi < 4; ++mi)
#pragma unroll
      for (int ni = 0; ni < 4; ++ni)
        acc[mi][ni] = __builtin_amdgcn_mfma_f32_16x16x32_bf16(af[mi], bfr[ni], acc[mi][ni], 0, 0, 0);
    __syncthreads();
    cur ^= 1;
  }

#pragma unroll
  for (int mi = 0; mi < 4; ++mi)
#pragma unroll
    for (int ni = 0; ni < 4; ++ni) {
      size_t row = arow0 + wr * 64 + mi * 16 + l4 * 4;
      size_t col = brow0 + wc * 64 + ni * 16 + l15;
#pragma unroll
      for (int r = 0; r < 4; ++r) {
        float v = acc[mi][ni][r];
        if constexpr (sizeof(OUT) == 4) Cm[(row + r) * N + col] = v;
        else                            Cm[(row + r) * N + col] = f2bf(v);
      }
    }
}

// ---------------- flash attention: QBLK=128 (4 waves x 32 q-rows), KVBLK=64, GQA
// K/V double-buffered (prefetch issued before compute, single barrier/iter).
// K/V/P LDS XOR-swizzled; K/V staged via global_load_lds with pre-swizzled source.
__global__ __launch_bounds__(256, 2) void attn_kernel(const unsigned short* __restrict__ qkv,
                                                      const unsigned short* __restrict__ vt,
                                                      unsigned short* __restrict__ att) {
  constexpr int KB = 64;
  __shared__ __align__(16) unsigned short Kl[2][KB * 128];   // 32KB, swizzled
  __shared__ __align__(16) unsigned short Vl[2][128 * KB];   // 32KB, swizzled
  __shared__ __align__(16) unsigned short Pl[4][32 * KB];    // per-wave P, 16KB, swizzled
  int tid = threadIdx.x, w = tid >> 6, lane = tid & 63;
  int l15 = lane & 15, l4 = lane >> 4;
  int q0 = blockIdx.x * 128;
  int bh = blockIdx.y, b = bh >> 4, h = bh & 15, kvh = h >> 2;
  int qr0 = q0 + w * 32;  // this wave's first q row

  // Q fragments in registers (2 row-tiles x 4 k-chunks), pre-scaled by 1/sqrt(HD)
  bf16x8 qf[2][4];
  {
    const unsigned short* qb = qkv + (size_t)(b * T_ + qr0 + l15) * NQKV_ + h * HD_;
    const float scale = 0.08838834764831845f;
#pragma unroll
    for (int mi = 0; mi < 2; ++mi)
#pragma unroll
      for (int kk = 0; kk < 4; ++kk) {
        bf16x8 t = *reinterpret_cast<const bf16x8*>(qb + (size_t)mi * 16 * NQKV_ + kk * 32 + l4 * 8);
#pragma unroll
        for (int j = 0; j < 8; ++j) t[j] = (__bf16)((float)t[j] * scale);
        qf[mi][kk] = t;
      }
  }

  f32x4 o[2][8];
  float mr[2][4], lr[2][4];
#pragma unroll
  for (int mi = 0; mi < 2; ++mi) {
#pragma unroll
    for (int di = 0; di < 8; ++di) o[mi][di] = (f32x4){0.f, 0.f, 0.f, 0.f};
#pragma unroll
    for (int r = 0; r < 4; ++r) { mr[mi][r] = -1e30f; lr[mi][r] = 0.f; }
  }

  auto stage = [&](int buf, int kv0) {
#pragma unroll
    for (int i = 0; i < 4; ++i) {  // K tile: chunk c ^= (row&7), row = c>>4
      int c = (i * 4 + w) * 64 + lane;
      int g = c ^ ((c >> 4) & 7);
      const unsigned short* src =
          qkv + (size_t)(b * T_ + kv0 + (g >> 4)) * NQKV_ + C_ + kvh * HD_ + (g & 15) * 8;
      GLOAD_LDS16(src, &Kl[buf][(i * 4 + w) * 512]);
    }
#pragma unroll
    for (int i = 0; i < 4; ++i) {  // V^T tile: chunk c ^= (row&7), row = c>>3
      int c = (i * 4 + w) * 64 + lane;
      int g = c ^ ((c >> 3) & 7);
      const unsigned short* src =
          vt + (size_t)((b * NKV_ + kvh) * HD_ + (g >> 3)) * T_ + kv0 + (g & 7) * 8;
      GLOAD_LDS16(src, &Vl[buf][(i * 4 + w) * 512]);
    }
  };

  int nt = q0 / KB + 2;  // causal: tiles up to q0+128
  stage(0, 0);
  __syncthreads();
  int cur = 0;
  for (int kt = 0; kt < nt; ++kt) {
    int kv0 = kt * KB;
    if (kt + 1 < nt) stage(cur ^ 1, kv0 + KB);  // prefetch: lands at the barrier below

    if (kv0 <= qr0 + 31) {  // wave-uniform: skip fully-masked tiles
      // S = Q K^T   (32 x 64 per wave)
      f32x4 s[2][4];
#pragma unroll
      for (int mi = 0; mi < 2; ++mi)
#pragma unroll
        for (int ni = 0; ni < 4; ++ni) s[mi][ni] = (f32x4){0.f, 0.f, 0.f, 0.f};
#pragma unroll
      for (int ni = 0; ni < 4; ++ni)
#pragma unroll
        for (int kk = 0; kk < 4; ++kk) {
          bf16x8 kf = *reinterpret_cast<const bf16x8*>(
              &Kl[cur][((ni * 16 + l15) * 128 + kk * 32 + l4 * 8) ^ ((l15 & 7) << 3)]);
#pragma unroll
          for (int mi = 0; mi < 2; ++mi)
            s[mi][ni] = __builtin_amdgcn_mfma_f32_16x16x32_bf16(qf[mi][kk], kf, s[mi][ni], 0, 0, 0);
        }

      // online softmax (rows live across 16 lanes; reduce with shfl_xor 1/2/4/8)
      bool need_mask = (kv0 + KB - 1) > qr0;
#pragma unroll
      for (int mi = 0; mi < 2; ++mi) {
        float alpha[4];
#pragma unroll
        for (int r = 0; r < 4; ++r) {
          int qrow = qr0 + mi * 16 + l4 * 4 + r;
          float rm = -1e30f;
#pragma unroll
          for (int ni = 0; ni < 4; ++ni) {
            float sv = s[mi][ni][r];
            if (need_mask && (kv0 + ni * 16 + l15 > qrow)) sv = -1e30f;
            s[mi][ni][r] = sv;
            rm = fmaxf(rm, sv);
          }
#pragma unroll
          for (int msk = 1; msk < 16; msk <<= 1) rm = fmaxf(rm, __shfl_xor(rm, msk));
          float mold = mr[mi][r];
          float mnew = fmaxf(mold, rm);
          mr[mi][r] = mnew;
          alpha[r] = __expf(mold - mnew);
          float ps = 0.f;
#pragma unroll
          for (int ni = 0; ni < 4; ++ni) {
            float p = __expf(s[mi][ni][r] - mnew);
            s[mi][ni][r] = p;
            ps += p;
          }
#pragma unroll
          for (int msk = 1; msk < 16; msk <<= 1) ps += __shfl_xor(ps, msk);
          lr[mi][r] = alpha[r] * lr[mi][r] + ps;
        }
        f32x4 av = {alpha[0], alpha[1], alpha[2], alpha[3]};
#pragma unroll
        for (int di = 0; di < 8; ++di) o[mi][di] *= av;
#pragma unroll
        for (int ni = 0; ni < 4; ++ni)
#pragma unroll
          for (int r = 0; r < 4; ++r) {
            int row = mi * 16 + l4 * 4 + r;
            Pl[w][((row * KB) + ni * 16 + l15) ^ ((row & 7) << 3)] = f2bf(s[mi][ni][r]);
          }
      }

      // O += P V  (P from per-wave swizzled LDS — wave-private, no barrier needed)
#pragma unroll
      for (int kk = 0; kk < 2; ++kk) {
        bf16x8 pa[2];
#pragma unroll
        for (int mi = 0; mi < 2; ++mi) {
          int row = mi * 16 + l15;
          pa[mi] = *reinterpret_cast<const bf16x8*>(
              &Pl[w][(row * KB + kk * 32 + l4 * 8) ^ ((row & 7) << 3)]);
        }
#pragma unroll
        for (int di = 0; di < 8; ++di) {
          bf16x8 vf = *reinterpret_cast<const bf16x8*>(
              &Vl[cur][((di * 16 + l15) * KB + kk * 32 + l4 * 8) ^ ((l15 & 7) << 3)]);
#pragma unroll
          for (int mi = 0; mi < 2; ++mi)
            o[mi][di] = __builtin_amdgcn_mfma_f32_16x16x32_bf16(pa[mi], vf, o[mi][di], 0, 0, 0);
        }
      }
    }

    __syncthreads();  // drains prefetch (vmcnt 0) + guards buffer reuse
    cur ^= 1;
  }

#pragma unroll
  for (int mi = 0; mi < 2; ++mi)
#pragma unroll
    for (int r = 0; r < 4; ++r) {
      float inv = 1.f / lr[mi][r];
      size_t row = (size_t)(b * T_ + qr0 + mi * 16 + l4 * 4 + r);
#pragma unroll
      for (int di = 0; di < 8; ++di)
        att[row * C_ + h * HD_ + di * 16 + l15] = f2bf(o[mi][di][r] * inv);
    }
}

extern "C" void kernel_launch(void* const* d_in, const int* in_sizes, int n_in,
                              void* d_out, int out_size, void* d_ws, size_t ws_size,
                              hipStream_t stream) {
  const float* x  = (const float*)d_in[0];
  const float* Wq = (const float*)d_in[1];
  const float* Wk = (const float*)d_in[2];
  const float* Wv = (const float*)d_in[3];
  const float* Wp = (const float*)d_in[4];
  float* out = (float*)d_out;
  char* ws = (char*)d_ws;

  // workspace layout (bytes); total 68,157,440
  unsigned short* xb  = (unsigned short*)(ws);              // 4096x2048 bf16 (reused as att)
  unsigned short* wt  = (unsigned short*)(ws + 16777216);   // 5120x2048 bf16 (Wq^T|Wk^T|Wv^T|Wp^T)
  unsigned short* qkv = (unsigned short*)(ws + 37748736);   // 4096x3072 bf16
  float2*         rt  = (float2*)(ws + 62914560);           // 2048x64 {cos,sin}
  unsigned short* vt  = (unsigned short*)(ws + 63963136);   // 8x128x2048 bf16
  unsigned short* att = xb;                                 // alias: xb dead after GEMM1

  rope_table_kernel<<<T_, 64, 0, stream>>>(rt);
  convx_kernel<<<(M_ * C_ / 4 + 255) / 256, 256, 0, stream>>>(x, xb, M_ * C_ / 4);
  transpose_conv_kernel<<<dim3(64, 64), 256, 0, stream>>>(Wq, wt, C_, C_);
  transpose_conv_kernel<<<dim3(16, 64), 256, 0, stream>>>(Wk, wt + (size_t)2048 * 2048, C_, 512);
  transpose_conv_kernel<<<dim3(16, 64), 256, 0, stream>>>(Wv, wt + (size_t)2560 * 2048, C_, 512);
  transpose_conv_kernel<<<dim3(64, 64), 256, 0, stream>>>(Wp, wt + (size_t)3072 * 2048, C_, 2048);

  gemm_bf16<unsigned short><<<dim3(NQKV_ / 128, M_ / 128), 256, 0, stream>>>(
      xb, wt, qkv, M_, NQKV_, C_);
  rope_kernel<<<(M_ * 160 + 255) / 256, 256, 0, stream>>>(qkv, rt);
  transpose_v_kernel<<<dim3(T_ / 32, HD_ / 32, B_ * NKV_), 256, 0, stream>>>(qkv, vt);
  attn_kernel<<<dim3(T_ / 128, B_ * NH_), 256, 0, stream>>>(qkv, vt, att);
  gemm_bf16<float><<<dim3(C_ / 128, M_ / 128), 256, 0, stream>>>(
      att, wt + (size_t)3072 * 2048, out, M_, C_, C_);
}

// Round 4
// 275.050 us; speedup vs baseline: 1.6673x; 1.2249x over previous
//
#include <hip/hip_runtime.h>

#define B_ 2
#define T_ 2048
#define C_ 2048
#define NH_ 16
#define NKV_ 4
#define HD_ 128
#define M_ 4096          // B*T
#define NQKV_ 3072       // C + 2*NKV*HD

typedef __bf16 bf16x8 __attribute__((ext_vector_type(8)));
typedef float f32x4 __attribute__((ext_vector_type(4)));

__device__ __forceinline__ unsigned short f2bf(float f) {
  union { float f; unsigned u; } c{f};
  unsigned u = c.u + 0x7FFFu + ((c.u >> 16) & 1u);
  return (unsigned short)(u >> 16);
}
__device__ __forceinline__ float bf2f(unsigned short h) {
  union { unsigned u; float f; } c{(unsigned)h << 16};
  return c.f;
}

#define GLOAD_LDS16(g, l)                                        \
  __builtin_amdgcn_global_load_lds(                              \
      (const __attribute__((address_space(1))) void*)(g),        \
      (__attribute__((address_space(3))) void*)(l), 16, 0, 0)

// ---------------- RoPE cos/sin table: rt[t*64+i] = {cos,sin}(t * 10000^(-2i/128))
__global__ void rope_table_kernel(float2* __restrict__ rt) {
  int t = blockIdx.x, i = threadIdx.x;  // 2048 x 64
  float inv = powf(10000.f, -(float)(2 * i) / 128.f);
  float s, c;
  sincosf((float)t * inv, &s, &c);
  rt[t * 64 + i] = make_float2(c, s);
}

// ---------------- x f32 -> bf16 (vectorized)
__global__ void convx_kernel(const float* __restrict__ x, unsigned short* __restrict__ xb, int n4) {
  int i = blockIdx.x * blockDim.x + threadIdx.x;
  if (i >= n4) return;
  float4 v = reinterpret_cast<const float4*>(x)[i];
  union { ushort4 u; unsigned short s[4]; } o;
  o.s[0] = f2bf(v.x); o.s[1] = f2bf(v.y); o.s[2] = f2bf(v.z); o.s[3] = f2bf(v.w);
  reinterpret_cast<ushort4*>(xb)[i] = o.u;
}

// ---------------- W (K x N, f32 row-major) -> Wt (N x K, bf16)
__global__ void transpose_conv_kernel(const float* __restrict__ W, unsigned short* __restrict__ Wt,
                                      int K, int N) {
  __shared__ float tile[32][33];
  int bx = blockIdx.x * 32;  // n
  int by = blockIdx.y * 32;  // k
  int tx = threadIdx.x & 31, ty = threadIdx.x >> 5;  // 32x8
#pragma unroll
  for (int r = 0; r < 32; r += 8)
    tile[ty + r][tx] = W[(size_t)(by + ty + r) * N + bx + tx];
  __syncthreads();
#pragma unroll
  for (int r = 0; r < 32; r += 8)
    Wt[(size_t)(bx + ty + r) * K + by + tx] = f2bf(tile[tx][ty + r]);
}

// ---------------- RoPE applied in-place to q (cols 0..2047) and k (cols 2048..2559)
__global__ void rope_kernel(unsigned short* __restrict__ qkv, const float2* __restrict__ rt) {
  int g = blockIdx.x * blockDim.x + threadIdx.x;
  if (g >= M_ * 160) return;          // 160 octet-pairs per row: 128 q + 32 k
  int m = g / 160, u = g - m * 160;
  int t = m & (T_ - 1);
  int io, col0;
  if (u < 128) { io = (u & 7) * 8; col0 = (u >> 3) * HD_ + io; }
  else         { int uu = u - 128; io = (uu & 7) * 8; col0 = C_ + (uu >> 3) * HD_ + io; }
  unsigned short* p = qkv + (size_t)m * NQKV_ + col0;
  union V8 { uint4 v; unsigned short s[8]; };
  V8 a, b, oa, ob;
  a.v = *reinterpret_cast<const uint4*>(p);
  b.v = *reinterpret_cast<const uint4*>(p + 64);
#pragma unroll
  for (int j = 0; j < 8; ++j) {
    float2 cs = rt[t * 64 + io + j];
    float x1 = bf2f(a.s[j]), x2 = bf2f(b.s[j]);
    oa.s[j] = f2bf(x1 * cs.x - x2 * cs.y);
    ob.s[j] = f2bf(x2 * cs.x + x1 * cs.y);
  }
  *reinterpret_cast<uint4*>(p) = oa.v;
  *reinterpret_cast<uint4*>(p + 64) = ob.v;
}

// ---------------- V slice of qkv -> vt[(b*NKV+kvh)*HD + d][t]  (bf16 transpose)
__global__ void transpose_v_kernel(const unsigned short* __restrict__ qkv,
                                   unsigned short* __restrict__ vt) {
  __shared__ unsigned short tile[32][33];
  int bh = blockIdx.z;                 // b*NKV + kvh
  int b = bh >> 2, kvh = bh & 3;
  int t0 = blockIdx.x * 32, d0 = blockIdx.y * 32;
  int tx = threadIdx.x & 31, ty = threadIdx.x >> 5;
#pragma unroll
  for (int r = 0; r < 32; r += 8)
    tile[ty + r][tx] = qkv[(size_t)(b * T_ + t0 + ty + r) * NQKV_ + 2560 + kvh * HD_ + d0 + tx];
  __syncthreads();
#pragma unroll
  for (int r = 0; r < 32; r += 8)
    vt[(size_t)(bh * HD_ + d0 + ty + r) * T_ + t0 + tx] = tile[tx][ty + r];
}

// ---------------- bf16 GEMM: C(MxN) = A(MxK) * Bt(NxK)^T, 128x128 tile, BK=32
template <typename OUT>
__global__ __launch_bounds__(256) void gemm_bf16(const unsigned short* __restrict__ A,
                                                 const unsigned short* __restrict__ Bt,
                                                 OUT* __restrict__ Cm,
                                                 int M, int N, int K) {
  constexpr int BK = 32;
  __shared__ __align__(16) unsigned short Al[2][128 * BK];
  __shared__ __align__(16) unsigned short Bl[2][128 * BK];
  int tid = threadIdx.x, w = tid >> 6, lane = tid & 63;
  int l15 = lane & 15, l4 = lane >> 4;
  int wr = w >> 1, wc = w & 1;  // wave -> 64x64 quadrant
  size_t arow0 = (size_t)blockIdx.y * 128;
  size_t brow0 = (size_t)blockIdx.x * 128;

  f32x4 acc[4][4];
#pragma unroll
  for (int mi = 0; mi < 4; ++mi)
#pragma unroll
    for (int ni = 0; ni < 4; ++ni) acc[mi][ni] = (f32x4){0.f, 0.f, 0.f, 0.f};

  auto stage = [&](int buf, int k0) {
#pragma unroll
    for (int i = 0; i < 2; ++i) {                 // A tile: 8KB = 8 wave-insts
      int c = i * 256 + w * 64 + lane;            // chunk 0..511 (16B each)
      const unsigned short* g = A + (arow0 + (c >> 2)) * K + k0 + (c & 3) * 8;
      GLOAD_LDS16(g, &Al[buf][(i * 4 + w) * 512]);
    }
#pragma unroll
    for (int i = 0; i < 2; ++i) {
      int c = i * 256 + w * 64 + lane;
      const unsigned short* g = Bt + (brow0 + (c >> 2)) * K + k0 + (c & 3) * 8;
      GLOAD_LDS16(g, &Bl[buf][(i * 4 + w) * 512]);
    }
  };

  stage(0, 0);
  __syncthreads();
  int NT = K / BK, cur = 0;
  for (int kt = 0; kt < NT; ++kt) {
    if (kt + 1 < NT) stage(cur ^ 1, (kt + 1) * BK);
    const unsigned short* Ab = &Al[cur][0];
    const unsigned short* Bb = &Bl[cur][0];
    bf16x8 af[4], bfr[4];
#pragma unroll
    for (int mi = 0; mi < 4; ++mi)
      af[mi] = *reinterpret_cast<const bf16x8*>(Ab + (wr * 64 + mi * 16 + l15) * BK + l4 * 8);
#pragma unroll
    for (int ni = 0; ni < 4; ++ni)
      bfr[ni] = *reinterpret_cast<const bf16x8*>(Bb + (wc * 64 + ni * 16 + l15) * BK + l4 * 8);
#pragma unroll
    for (int mi = 0; mi < 4; ++mi)
#pragma unroll
      for (int ni = 0; ni < 4; ++ni)
        acc[mi][ni] = __builtin_amdgcn_mfma_f32_16x16x32_bf16(af[mi], bfr[ni], acc[mi][ni], 0, 0, 0);
    __syncthreads();
    cur ^= 1;
  }

#pragma unroll
  for (int mi = 0; mi < 4; ++mi)
#pragma unroll
    for (int ni = 0; ni < 4; ++ni) {
      size_t row = arow0 + wr * 64 + mi * 16 + l4 * 4;
      size_t col = brow0 + wc * 64 + ni * 16 + l15;
#pragma unroll
      for (int r = 0; r < 4; ++r) {
        float v = acc[mi][ni][r];
        if constexpr (sizeof(OUT) == 4) Cm[(row + r) * N + col] = v;
        else                            Cm[(row + r) * N + col] = f2bf(v);
      }
    }
}

// ---------------- flash attention: QBLK=128 (4 waves x 32 q-rows), KVBLK=64, GQA
// Work-balanced 1D grid (q-tile pairing), dbuf K/V prefetch, swizzled LDS,
// defer-max (THR=8), deferred l-sum reduction, setprio around MFMA clusters.
__global__ __launch_bounds__(256, 2) void attn_kernel(const unsigned short* __restrict__ qkv,
                                                      const unsigned short* __restrict__ vt,
                                                      unsigned short* __restrict__ att) {
  constexpr int KB = 64;
  __shared__ __align__(16) unsigned short Kl[2][KB * 128];   // 32KB, swizzled
  __shared__ __align__(16) unsigned short Vl[2][128 * KB];   // 32KB, swizzled
  __shared__ __align__(16) unsigned short Pl[4][32 * KB];    // per-wave P, 16KB, swizzled
  int tid = threadIdx.x, w = tid >> 6, lane = tid & 63;
  int l15 = lane & 15, l4 = lane >> 4;

  // balanced decode: ids k and k+256 get q-tiles summing to 15 (const work/CU
  // under round-robin dispatch)
  int id = blockIdx.x;
  int u = id & 255, half = id >> 8;
  int bh = u & 31;
  int qh = u >> 5;                       // 0..7
  int qi = half ? (15 - qh) : qh;        // 0..15
  int q0 = qi * 128;
  int b = bh >> 4, h = bh & 15, kvh = h >> 2;
  int qr0 = q0 + w * 32;  // this wave's first q row

  // Q fragments in registers (2 row-tiles x 4 k-chunks), pre-scaled by 1/sqrt(HD)
  bf16x8 qf[2][4];
  {
    const unsigned short* qb = qkv + (size_t)(b * T_ + qr0 + l15) * NQKV_ + h * HD_;
    const float scale = 0.08838834764831845f;
#pragma unroll
    for (int mi = 0; mi < 2; ++mi)
#pragma unroll
      for (int kk = 0; kk < 4; ++kk) {
        bf16x8 t = *reinterpret_cast<const bf16x8*>(qb + (size_t)mi * 16 * NQKV_ + kk * 32 + l4 * 8);
#pragma unroll
        for (int j = 0; j < 8; ++j) t[j] = (__bf16)((float)t[j] * scale);
        qf[mi][kk] = t;
      }
  }

  f32x4 o[2][8];
  float mr[2][4], lr[2][4];
#pragma unroll
  for (int mi = 0; mi < 2; ++mi) {
#pragma unroll
    for (int di = 0; di < 8; ++di) o[mi][di] = (f32x4){0.f, 0.f, 0.f, 0.f};
#pragma unroll
    for (int r = 0; r < 4; ++r) { mr[mi][r] = -1e30f; lr[mi][r] = 0.f; }
  }

  auto stage = [&](int buf, int kv0) {
#pragma unroll
    for (int i = 0; i < 4; ++i) {  // K tile: chunk c ^= (row&7), row = c>>4
      int c = (i * 4 + w) * 64 + lane;
      int g = c ^ ((c >> 4) & 7);
      const unsigned short* src =
          qkv + (size_t)(b * T_ + kv0 + (g >> 4)) * NQKV_ + C_ + kvh * HD_ + (g & 15) * 8;
      GLOAD_LDS16(src, &Kl[buf][(i * 4 + w) * 512]);
    }
#pragma unroll
    for (int i = 0; i < 4; ++i) {  // V^T tile: chunk c ^= (row&7), row = c>>3
      int c = (i * 4 + w) * 64 + lane;
      int g = c ^ ((c >> 3) & 7);
      const unsigned short* src =
          vt + (size_t)((b * NKV_ + kvh) * HD_ + (g >> 3)) * T_ + kv0 + (g & 7) * 8;
      GLOAD_LDS16(src, &Vl[buf][(i * 4 + w) * 512]);
    }
  };

  int nt = q0 / KB + 2;  // causal: tiles up to q0+128
  stage(0, 0);
  __syncthreads();
  int cur = 0;
  for (int kt = 0; kt < nt; ++kt) {
    int kv0 = kt * KB;
    if (kt + 1 < nt) stage(cur ^ 1, kv0 + KB);  // prefetch: lands at the barrier below

    if (kv0 <= qr0 + 31) {  // wave-uniform: skip fully-masked tiles
      // S = Q K^T   (32 x 64 per wave)
      f32x4 s[2][4];
#pragma unroll
      for (int mi = 0; mi < 2; ++mi)
#pragma unroll
        for (int ni = 0; ni < 4; ++ni) s[mi][ni] = (f32x4){0.f, 0.f, 0.f, 0.f};
      __builtin_amdgcn_s_setprio(1);
#pragma unroll
      for (int ni = 0; ni < 4; ++ni)
#pragma unroll
        for (int kk = 0; kk < 4; ++kk) {
          bf16x8 kf = *reinterpret_cast<const bf16x8*>(
              &Kl[cur][((ni * 16 + l15) * 128 + kk * 32 + l4 * 8) ^ ((l15 & 7) << 3)]);
#pragma unroll
          for (int mi = 0; mi < 2; ++mi)
            s[mi][ni] = __builtin_amdgcn_mfma_f32_16x16x32_bf16(qf[mi][kk], kf, s[mi][ni], 0, 0, 0);
        }
      __builtin_amdgcn_s_setprio(0);

      // online softmax: mask, row-max reduce (4 shfl rounds); l-sum kept as
      // per-lane partial (reduced once in epilogue); defer-max THR=8
      bool need_mask = (kv0 + KB - 1) > qr0;
      float rmv[2][4];
#pragma unroll
      for (int mi = 0; mi < 2; ++mi)
#pragma unroll
        for (int r = 0; r < 4; ++r) {
          int qrow = qr0 + mi * 16 + l4 * 4 + r;
          float rm = -1e30f;
#pragma unroll
          for (int ni = 0; ni < 4; ++ni) {
            float sv = s[mi][ni][r];
            if (need_mask && (kv0 + ni * 16 + l15 > qrow)) sv = -1e30f;
            s[mi][ni][r] = sv;
            rm = fmaxf(rm, sv);
          }
#pragma unroll
          for (int msk = 1; msk < 16; msk <<= 1) rm = fmaxf(rm, __shfl_xor(rm, msk));
          rmv[mi][r] = rm;
        }
      bool okf = true;
#pragma unroll
      for (int mi = 0; mi < 2; ++mi)
#pragma unroll
        for (int r = 0; r < 4; ++r) okf = okf && (rmv[mi][r] <= mr[mi][r] + 8.f);
      if (!__all(okf)) {
#pragma unroll
        for (int mi = 0; mi < 2; ++mi) {
          float alpha[4];
#pragma unroll
          for (int r = 0; r < 4; ++r) {
            float mnew = fmaxf(mr[mi][r], rmv[mi][r]);
            alpha[r] = __expf(mr[mi][r] - mnew);
            mr[mi][r] = mnew;
            lr[mi][r] *= alpha[r];
          }
          f32x4 av = {alpha[0], alpha[1], alpha[2], alpha[3]};
#pragma unroll
          for (int di = 0; di < 8; ++di) o[mi][di] *= av;
        }
      }
#pragma unroll
      for (int mi = 0; mi < 2; ++mi) {
#pragma unroll
        for (int r = 0; r < 4; ++r) {
          float m = mr[mi][r];
          float ps = 0.f;
#pragma unroll
          for (int ni = 0; ni < 4; ++ni) {
            float p = __expf(s[mi][ni][r] - m);
            s[mi][ni][r] = p;
            ps += p;
          }
          lr[mi][r] += ps;  // per-lane partial
        }
#pragma unroll
        for (int ni = 0; ni < 4; ++ni)
#pragma unroll
          for (int r = 0; r < 4; ++r) {
            int row = mi * 16 + l4 * 4 + r;
            Pl[w][((row * KB) + ni * 16 + l15) ^ ((row & 7) << 3)] = f2bf(s[mi][ni][r]);
          }
      }

      // O += P V  (P from per-wave swizzled LDS — wave-private, no barrier needed)
      __builtin_amdgcn_s_setprio(1);
#pragma unroll
      for (int kk = 0; kk < 2; ++kk) {
        bf16x8 pa[2];
#pragma unroll
        for (int mi = 0; mi < 2; ++mi) {
          int row = mi * 16 + l15;
          pa[mi] = *reinterpret_cast<const bf16x8*>(
              &Pl[w][(row * KB + kk * 32 + l4 * 8) ^ ((row & 7) << 3)]);
        }
#pragma unroll
        for (int di = 0; di < 8; ++di) {
          bf16x8 vf = *reinterpret_cast<const bf16x8*>(
              &Vl[cur][((di * 16 + l15) * KB + kk * 32 + l4 * 8) ^ ((l15 & 7) << 3)]);
#pragma unroll
          for (int mi = 0; mi < 2; ++mi)
            o[mi][di] = __builtin_amdgcn_mfma_f32_16x16x32_bf16(pa[mi], vf, o[mi][di], 0, 0, 0);
        }
      }
      __builtin_amdgcn_s_setprio(0);
    }

    __syncthreads();  // drains prefetch (vmcnt 0) + guards buffer reuse
    cur ^= 1;
  }

#pragma unroll
  for (int mi = 0; mi < 2; ++mi)
#pragma unroll
    for (int r = 0; r < 4; ++r) {
      float ls = lr[mi][r];
#pragma unroll
      for (int msk = 1; msk < 16; msk <<= 1) ls += __shfl_xor(ls, msk);
      float inv = 1.f / ls;
      size_t row = (size_t)(b * T_ + qr0 + mi * 16 + l4 * 4 + r);
#pragma unroll
      for (int di = 0; di < 8; ++di)
        att[row * C_ + h * HD_ + di * 16 + l15] = f2bf(o[mi][di][r] * inv);
    }
}

extern "C" void kernel_launch(void* const* d_in, const int* in_sizes, int n_in,
                              void* d_out, int out_size, void* d_ws, size_t ws_size,
                              hipStream_t stream) {
  const float* x  = (const float*)d_in[0];
  const float* Wq = (const float*)d_in[1];
  const float* Wk = (const float*)d_in[2];
  const float* Wv = (const float*)d_in[3];
  const float* Wp = (const float*)d_in[4];
  float* out = (float*)d_out;
  char* ws = (char*)d_ws;

  // workspace layout (bytes); total 68,157,440
  unsigned short* xb  = (unsigned short*)(ws);              // 4096x2048 bf16 (reused as att)
  unsigned short* wt  = (unsigned short*)(ws + 16777216);   // 5120x2048 bf16 (Wq^T|Wk^T|Wv^T|Wp^T)
  unsigned short* qkv = (unsigned short*)(ws + 37748736);   // 4096x3072 bf16
  float2*         rt  = (float2*)(ws + 62914560);           // 2048x64 {cos,sin}
  unsigned short* vt  = (unsigned short*)(ws + 63963136);   // 8x128x2048 bf16
  unsigned short* att = xb;                                 // alias: xb dead after GEMM1

  rope_table_kernel<<<T_, 64, 0, stream>>>(rt);
  convx_kernel<<<(M_ * C_ / 4 + 255) / 256, 256, 0, stream>>>(x, xb, M_ * C_ / 4);
  transpose_conv_kernel<<<dim3(64, 64), 256, 0, stream>>>(Wq, wt, C_, C_);
  transpose_conv_kernel<<<dim3(16, 64), 256, 0, stream>>>(Wk, wt + (size_t)2048 * 2048, C_, 512);
  transpose_conv_kernel<<<dim3(16, 64), 256, 0, stream>>>(Wv, wt + (size_t)2560 * 2048, C_, 512);
  transpose_conv_kernel<<<dim3(64, 64), 256, 0, stream>>>(Wp, wt + (size_t)3072 * 2048, C_, 2048);

  gemm_bf16<unsigned short><<<dim3(NQKV_ / 128, M_ / 128), 256, 0, stream>>>(
      xb, wt, qkv, M_, NQKV_, C_);
  rope_kernel<<<(M_ * 160 + 255) / 256, 256, 0, stream>>>(qkv, rt);
  transpose_v_kernel<<<dim3(T_ / 32, HD_ / 32, B_ * NKV_), 256, 0, stream>>>(qkv, vt);
  attn_kernel<<<dim3(512), 256, 0, stream>>>(qkv, vt, att);
  gemm_bf16<float><<<dim3(C_ / 128, M_ / 128), 256, 0, stream>>>(
      att, wt + (size_t)3072 * 2048, out, M_, C_, C_);
}

// Round 5
// 233.957 us; speedup vs baseline: 1.9601x; 1.1756x over previous
//
#include <hip/hip_runtime.h>

#define B_ 2
#define T_ 2048
#define C_ 2048
#define NH_ 16
#define NKV_ 4
#define HD_ 128
#define M_ 4096          // B*T
#define NQKV_ 3072       // C + 2*NKV*HD

typedef __bf16 bf16x8 __attribute__((ext_vector_type(8)));
typedef float f32x4 __attribute__((ext_vector_type(4)));
typedef float f32x16 __attribute__((ext_vector_type(16)));

__device__ __forceinline__ unsigned short f2bf(float f) {
  union { float f; unsigned u; } c{f};
  unsigned u = c.u + 0x7FFFu + ((c.u >> 16) & 1u);
  return (unsigned short)(u >> 16);
}
__device__ __forceinline__ float bf2f(unsigned short h) {
  union { unsigned u; float f; } c{(unsigned)h << 16};
  return c.f;
}

#define GLOAD_LDS16(g, l)                                        \
  __builtin_amdgcn_global_load_lds(                              \
      (const __attribute__((address_space(1))) void*)(g),        \
      (__attribute__((address_space(3))) void*)(l), 16, 0, 0)

// ---------------- RoPE cos/sin table: rt[t*64+i] = {cos,sin}(t * 10000^(-2i/128))
__global__ void rope_table_kernel(float2* __restrict__ rt) {
  int t = blockIdx.x, i = threadIdx.x;  // 2048 x 64
  float inv = powf(10000.f, -(float)(2 * i) / 128.f);
  float s, c;
  sincosf((float)t * inv, &s, &c);
  rt[t * 64 + i] = make_float2(c, s);
}

// ---------------- x f32 -> bf16 (vectorized)
__global__ void convx_kernel(const float* __restrict__ x, unsigned short* __restrict__ xb, int n4) {
  int i = blockIdx.x * blockDim.x + threadIdx.x;
  if (i >= n4) return;
  float4 v = reinterpret_cast<const float4*>(x)[i];
  union { ushort4 u; unsigned short s[4]; } o;
  o.s[0] = f2bf(v.x); o.s[1] = f2bf(v.y); o.s[2] = f2bf(v.z); o.s[3] = f2bf(v.w);
  reinterpret_cast<ushort4*>(xb)[i] = o.u;
}

// ---------------- W (K x N, f32 row-major) -> Wt (N x K, bf16)
__global__ void transpose_conv_kernel(const float* __restrict__ W, unsigned short* __restrict__ Wt,
                                      int K, int N) {
  __shared__ float tile[32][33];
  int bx = blockIdx.x * 32;  // n
  int by = blockIdx.y * 32;  // k
  int tx = threadIdx.x & 31, ty = threadIdx.x >> 5;  // 32x8
#pragma unroll
  for (int r = 0; r < 32; r += 8)
    tile[ty + r][tx] = W[(size_t)(by + ty + r) * N + bx + tx];
  __syncthreads();
#pragma unroll
  for (int r = 0; r < 32; r += 8)
    Wt[(size_t)(bx + ty + r) * K + by + tx] = f2bf(tile[tx][ty + r]);
}

// ---------------- RoPE applied in-place to q (cols 0..2047) and k (cols 2048..2559)
__global__ void rope_kernel(unsigned short* __restrict__ qkv, const float2* __restrict__ rt) {
  int g = blockIdx.x * blockDim.x + threadIdx.x;
  if (g >= M_ * 160) return;          // 160 octet-pairs per row: 128 q + 32 k
  int m = g / 160, u = g - m * 160;
  int t = m & (T_ - 1);
  int io, col0;
  if (u < 128) { io = (u & 7) * 8; col0 = (u >> 3) * HD_ + io; }
  else         { int uu = u - 128; io = (uu & 7) * 8; col0 = C_ + (uu >> 3) * HD_ + io; }
  unsigned short* p = qkv + (size_t)m * NQKV_ + col0;
  union V8 { uint4 v; unsigned short s[8]; };
  V8 a, b, oa, ob;
  a.v = *reinterpret_cast<const uint4*>(p);
  b.v = *reinterpret_cast<const uint4*>(p + 64);
#pragma unroll
  for (int j = 0; j < 8; ++j) {
    float2 cs = rt[t * 64 + io + j];
    float x1 = bf2f(a.s[j]), x2 = bf2f(b.s[j]);
    oa.s[j] = f2bf(x1 * cs.x - x2 * cs.y);
    ob.s[j] = f2bf(x2 * cs.x + x1 * cs.y);
  }
  *reinterpret_cast<uint4*>(p) = oa.v;
  *reinterpret_cast<uint4*>(p + 64) = ob.v;
}

// ---------------- V slice of qkv -> vt[(b*NKV+kvh)*HD + d][t]  (bf16 transpose)
__global__ void transpose_v_kernel(const unsigned short* __restrict__ qkv,
                                   unsigned short* __restrict__ vt) {
  __shared__ unsigned short tile[32][33];
  int bh = blockIdx.z;                 // b*NKV + kvh
  int b = bh >> 2, kvh = bh & 3;
  int t0 = blockIdx.x * 32, d0 = blockIdx.y * 32;
  int tx = threadIdx.x & 31, ty = threadIdx.x >> 5;
#pragma unroll
  for (int r = 0; r < 32; r += 8)
    tile[ty + r][tx] = qkv[(size_t)(b * T_ + t0 + ty + r) * NQKV_ + 2560 + kvh * HD_ + d0 + tx];
  __syncthreads();
#pragma unroll
  for (int r = 0; r < 32; r += 8)
    vt[(size_t)(bh * HD_ + d0 + ty + r) * T_ + t0 + tx] = tile[tx][ty + r];
}

// ---------------- bf16 GEMM: C(MxN) = A(MxK) * Bt(NxK)^T, 128x128 tile, BK=32
template <typename OUT>
__global__ __launch_bounds__(256) void gemm_bf16(const unsigned short* __restrict__ A,
                                                 const unsigned short* __restrict__ Bt,
                                                 OUT* __restrict__ Cm,
                                                 int M, int N, int K) {
  constexpr int BK = 32;
  __shared__ __align__(16) unsigned short Al[2][128 * BK];
  __shared__ __align__(16) unsigned short Bl[2][128 * BK];
  int tid = threadIdx.x, w = tid >> 6, lane = tid & 63;
  int l15 = lane & 15, l4 = lane >> 4;
  int wr = w >> 1, wc = w & 1;  // wave -> 64x64 quadrant
  size_t arow0 = (size_t)blockIdx.y * 128;
  size_t brow0 = (size_t)blockIdx.x * 128;

  f32x4 acc[4][4];
#pragma unroll
  for (int mi = 0; mi < 4; ++mi)
#pragma unroll
    for (int ni = 0; ni < 4; ++ni) acc[mi][ni] = (f32x4){0.f, 0.f, 0.f, 0.f};

  auto stage = [&](int buf, int k0) {
#pragma unroll
    for (int i = 0; i < 2; ++i) {                 // A tile: 8KB = 8 wave-insts
      int c = i * 256 + w * 64 + lane;            // chunk 0..511 (16B each)
      const unsigned short* g = A + (arow0 + (c >> 2)) * K + k0 + (c & 3) * 8;
      GLOAD_LDS16(g, &Al[buf][(i * 4 + w) * 512]);
    }
#pragma unroll
    for (int i = 0; i < 2; ++i) {
      int c = i * 256 + w * 64 + lane;
      const unsigned short* g = Bt + (brow0 + (c >> 2)) * K + k0 + (c & 3) * 8;
      GLOAD_LDS16(g, &Bl[buf][(i * 4 + w) * 512]);
    }
  };

  stage(0, 0);
  __syncthreads();
  int NT = K / BK, cur = 0;
  for (int kt = 0; kt < NT; ++kt) {
    if (kt + 1 < NT) stage(cur ^ 1, (kt + 1) * BK);
    const unsigned short* Ab = &Al[cur][0];
    const unsigned short* Bb = &Bl[cur][0];
    bf16x8 af[4], bfr[4];
#pragma unroll
    for (int mi = 0; mi < 4; ++mi)
      af[mi] = *reinterpret_cast<const bf16x8*>(Ab + (wr * 64 + mi * 16 + l15) * BK + l4 * 8);
#pragma unroll
    for (int ni = 0; ni < 4; ++ni)
      bfr[ni] = *reinterpret_cast<const bf16x8*>(Bb + (wc * 64 + ni * 16 + l15) * BK + l4 * 8);
#pragma unroll
    for (int mi = 0; mi < 4; ++mi)
#pragma unroll
      for (int ni = 0; ni < 4; ++ni)
        acc[mi][ni] = __builtin_amdgcn_mfma_f32_16x16x32_bf16(af[mi], bfr[ni], acc[mi][ni], 0, 0, 0);
    __syncthreads();
    cur ^= 1;
  }

#pragma unroll
  for (int mi = 0; mi < 4; ++mi)
#pragma unroll
    for (int ni = 0; ni < 4; ++ni) {
      size_t row = arow0 + wr * 64 + mi * 16 + l4 * 4;
      size_t col = brow0 + wc * 64 + ni * 16 + l15;
#pragma unroll
      for (int r = 0; r < 4; ++r) {
        float v = acc[mi][ni][r];
        if constexpr (sizeof(OUT) == 4) Cm[(row + r) * N + col] = v;
        else                            Cm[(row + r) * N + col] = f2bf(v);
      }
    }
}

// ---------------- flash attention: QBLK=128 (4 waves x 32 q-rows), KVBLK=64, GQA
// 32x32 MFMA, swapped QK^T (S^T = K Q^T) -> softmax fully in-register
// (q = lane&31 per lane; row-reduce = in-lane + 1 shfl_xor(32)); P^T fragments
// assembled via xor-32 exchange (no P LDS). Balanced 1D grid, dbuf K/V,
// swizzled LDS, defer-max THR=8, setprio around MFMA clusters.
__global__ __launch_bounds__(256, 2) void attn_kernel(const unsigned short* __restrict__ qkv,
                                                      const unsigned short* __restrict__ vt,
                                                      unsigned short* __restrict__ att) {
  constexpr int KB = 64;
  __shared__ __align__(16) unsigned short Kl[2][KB * 128];   // [kv][d] 32KB, swizzled
  __shared__ __align__(16) unsigned short Vl[2][128 * KB];   // [d][kv] 32KB, swizzled
  int tid = threadIdx.x, w = tid >> 6, lane = tid & 63;
  int l31 = lane & 31, hi = lane >> 5;
  int h4 = hi * 4;

  // balanced decode: ids k and k+256 get q-tiles summing to 15 (const work/CU
  // under round-robin dispatch)
  int id = blockIdx.x;
  int u = id & 255, half = id >> 8;
  int bh = u & 31;
  int qh = u >> 5;                       // 0..7
  int qi = half ? (15 - qh) : qh;        // 0..15
  int q0 = qi * 128;
  int b = bh >> 4, hd = bh & 15, kvh = hd >> 2;
  int qr0 = q0 + w * 32;   // this wave's first q row
  int ql = qr0 + l31;      // this lane's q row

  // Q^T B-fragments: lane holds Q[ql][df*16 + hi*8 + j], pre-scaled by 1/sqrt(HD)
  bf16x8 qf[8];
  {
    const unsigned short* qb = qkv + (size_t)(b * T_ + ql) * NQKV_ + hd * HD_ + hi * 8;
    const float scale = 0.08838834764831845f;
#pragma unroll
    for (int df = 0; df < 8; ++df) {
      bf16x8 t = *reinterpret_cast<const bf16x8*>(qb + df * 16);
#pragma unroll
      for (int j = 0; j < 8; ++j) t[j] = (__bf16)((float)t[j] * scale);
      qf[df] = t;
    }
  }

  f32x16 o[4];  // O^T accumulators: d-tile dt: d = dt*32 + (r&3)+8*(r>>2)+h4, col q=l31
#pragma unroll
  for (int dt = 0; dt < 4; ++dt)
#pragma unroll
    for (int r = 0; r < 16; ++r) o[dt][r] = 0.f;
  float mr = -1e30f, lr = 0.f;

  auto stage = [&](int buf, int kv0) {
#pragma unroll
    for (int i = 0; i < 4; ++i) {  // K tile: chunk c ^= (row&7), row = c>>4
      int c = (i * 4 + w) * 64 + lane;
      int g = c ^ ((c >> 4) & 7);
      const unsigned short* src =
          qkv + (size_t)(b * T_ + kv0 + (g >> 4)) * NQKV_ + C_ + kvh * HD_ + (g & 15) * 8;
      GLOAD_LDS16(src, &Kl[buf][(i * 4 + w) * 512]);
    }
#pragma unroll
    for (int i = 0; i < 4; ++i) {  // V^T tile: chunk c ^= (row&7), row = c>>3
      int c = (i * 4 + w) * 64 + lane;
      int g = c ^ ((c >> 3) & 7);
      const unsigned short* src =
          vt + (size_t)((b * NKV_ + kvh) * HD_ + (g >> 3)) * T_ + kv0 + (g & 7) * 8;
      GLOAD_LDS16(src, &Vl[buf][(i * 4 + w) * 512]);
    }
  };

  int nt = q0 / KB + 2;  // causal: tiles up to q0+128
  stage(0, 0);
  __syncthreads();
  int cur = 0;
  for (int kt = 0; kt < nt; ++kt) {
    int kv0 = kt * KB;
    if (kt + 1 < nt) stage(cur ^ 1, kv0 + KB);  // prefetch: lands at the barrier below

    if (kv0 <= qr0 + 31) {  // wave-uniform: skip fully-masked tiles
      // S^T = K Q^T  (64k x 32q per wave); lane: q=l31, k = t2*32 + (r&3)+8(r>>2)+h4
      f32x16 s[2];
#pragma unroll
      for (int r = 0; r < 16; ++r) { s[0][r] = 0.f; s[1][r] = 0.f; }
      __builtin_amdgcn_s_setprio(1);
#pragma unroll
      for (int t2 = 0; t2 < 2; ++t2)
#pragma unroll
        for (int df = 0; df < 8; ++df) {
          bf16x8 kf = *reinterpret_cast<const bf16x8*>(
              &Kl[cur][((t2 * 32 + l31) * 128 + df * 16 + hi * 8) ^ ((l31 & 7) << 3)]);
          s[t2] = __builtin_amdgcn_mfma_f32_32x32x16_bf16(kf, qf[df], s[t2], 0, 0, 0);
        }
      __builtin_amdgcn_s_setprio(0);

      // mask + row-max (in-lane over 32 vals + one cross-half shfl)
      bool need_mask = (kv0 + KB - 1) > qr0;
      float rm = -1e30f;
#pragma unroll
      for (int t2 = 0; t2 < 2; ++t2)
#pragma unroll
        for (int r = 0; r < 16; ++r) {
          float sv = s[t2][r];
          int kcol = kv0 + t2 * 32 + (r & 3) + 8 * (r >> 2) + h4;
          if (need_mask && kcol > ql) sv = -1e30f;
          s[t2][r] = sv;
          rm = fmaxf(rm, sv);
        }
      rm = fmaxf(rm, __shfl_xor(rm, 32));

      // defer-max (THR=8)
      if (!__all(rm <= mr + 8.f)) {
        float mnew = fmaxf(mr, rm);
        float alpha = __expf(mr - mnew);
        mr = mnew;
        lr *= alpha;
#pragma unroll
        for (int dt = 0; dt < 4; ++dt)
#pragma unroll
          for (int r = 0; r < 16; ++r) o[dt][r] *= alpha;
      }

      // exp + per-lane partial sum (cross-half reduce deferred to epilogue)
      float ps = 0.f;
#pragma unroll
      for (int t2 = 0; t2 < 2; ++t2)
#pragma unroll
        for (int r = 0; r < 16; ++r) {
          float p = __expf(s[t2][r] - mr);
          s[t2][r] = p;
          ps += p;
        }
      lr += ps;

      // pack P to bf16 pairs: pk[t2][i] = {P(k=2i), P(k=2i+1)} for this lane's q
      unsigned pk[2][8];
#pragma unroll
      for (int t2 = 0; t2 < 2; ++t2)
#pragma unroll
        for (int i = 0; i < 8; ++i) {
          union { unsigned u32; __bf16 hh[2]; } pr;
          pr.hh[0] = (__bf16)s[t2][2 * i];
          pr.hh[1] = (__bf16)s[t2][2 * i + 1];
          pk[t2][i] = pr.u32;
        }

      // assemble P^T B-frags: elem j of frag f from lane (j>>2 half, same q),
      // pair idx 4*(f&1) + 2*hi + (dword&1); xor-32 exchange, 2 dwords per shfl pair
      bf16x8 pb[4];
#pragma unroll
      for (int f = 0; f < 4; ++f) {
        int t2 = f >> 1, bq = (f & 1) * 4;
        union { bf16x8 v; unsigned d[4]; } fr;
#pragma unroll
        for (int p = 0; p < 2; ++p) {
          unsigned uu = pk[t2][bq + p];          // consumed by hi=0 lanes
          unsigned ww = pk[t2][bq + 2 + p];      // consumed by hi=1 lanes
          unsigned us = (unsigned)__shfl_xor((int)uu, 32);
          unsigned ws = (unsigned)__shfl_xor((int)ww, 32);
          fr.d[p]     = hi ? ws : uu;
          fr.d[2 + p] = hi ? ww : us;
        }
        pb[f] = fr.v;
      }

      // O^T += V^T P^T
      __builtin_amdgcn_s_setprio(1);
#pragma unroll
      for (int dt = 0; dt < 4; ++dt)
#pragma unroll
        for (int kf = 0; kf < 4; ++kf) {
          bf16x8 vf = *reinterpret_cast<const bf16x8*>(
              &Vl[cur][((dt * 32 + l31) * KB + kf * 16 + hi * 8) ^ ((l31 & 7) << 3)]);
          o[dt] = __builtin_amdgcn_mfma_f32_32x32x16_bf16(vf, pb[kf], o[dt], 0, 0, 0);
        }
      __builtin_amdgcn_s_setprio(0);
    }

    __syncthreads();  // drains prefetch (vmcnt 0) + guards buffer reuse
    cur ^= 1;
  }

  // epilogue: finish l reduce, normalize, scatter O^T back to att[q][d]
  float ls = lr + __shfl_xor(lr, 32);
  float inv = 1.f / ls;
  unsigned short* ob = att + (size_t)(b * T_ + ql) * C_ + hd * HD_;
#pragma unroll
  for (int dt = 0; dt < 4; ++dt)
#pragma unroll
    for (int r = 0; r < 16; ++r) {
      int d = dt * 32 + (r & 3) + 8 * (r >> 2) + h4;
      ob[d] = f2bf(o[dt][r] * inv);
    }
}

extern "C" void kernel_launch(void* const* d_in, const int* in_sizes, int n_in,
                              void* d_out, int out_size, void* d_ws, size_t ws_size,
                              hipStream_t stream) {
  const float* x  = (const float*)d_in[0];
  const float* Wq = (const float*)d_in[1];
  const float* Wk = (const float*)d_in[2];
  const float* Wv = (const float*)d_in[3];
  const float* Wp = (const float*)d_in[4];
  float* out = (float*)d_out;
  char* ws = (char*)d_ws;

  // workspace layout (bytes); total 68,157,440
  unsigned short* xb  = (unsigned short*)(ws);              // 4096x2048 bf16 (reused as att)
  unsigned short* wt  = (unsigned short*)(ws + 16777216);   // 5120x2048 bf16 (Wq^T|Wk^T|Wv^T|Wp^T)
  unsigned short* qkv = (unsigned short*)(ws + 37748736);   // 4096x3072 bf16
  float2*         rt  = (float2*)(ws + 62914560);           // 2048x64 {cos,sin}
  unsigned short* vt  = (unsigned short*)(ws + 63963136);   // 8x128x2048 bf16
  unsigned short* att = xb;                                 // alias: xb dead after GEMM1

  rope_table_kernel<<<T_, 64, 0, stream>>>(rt);
  convx_kernel<<<(M_ * C_ / 4 + 255) / 256, 256, 0, stream>>>(x, xb, M_ * C_ / 4);
  transpose_conv_kernel<<<dim3(64, 64), 256, 0, stream>>>(Wq, wt, C_, C_);
  transpose_conv_kernel<<<dim3(16, 64), 256, 0, stream>>>(Wk, wt + (size_t)2048 * 2048, C_, 512);
  transpose_conv_kernel<<<dim3(16, 64), 256, 0, stream>>>(Wv, wt + (size_t)2560 * 2048, C_, 512);
  transpose_conv_kernel<<<dim3(64, 64), 256, 0, stream>>>(Wp, wt + (size_t)3072 * 2048, C_, 2048);

  gemm_bf16<unsigned short><<<dim3(NQKV_ / 128, M_ / 128), 256, 0, stream>>>(
      xb, wt, qkv, M_, NQKV_, C_);
  rope_kernel<<<(M_ * 160 + 255) / 256, 256, 0, stream>>>(qkv, rt);
  transpose_v_kernel<<<dim3(T_ / 32, HD_ / 32, B_ * NKV_), 256, 0, stream>>>(qkv, vt);
  attn_kernel<<<dim3(512), 256, 0, stream>>>(qkv, vt, att);
  gemm_bf16<float><<<dim3(C_ / 128, M_ / 128), 256, 0, stream>>>(
      att, wt + (size_t)3072 * 2048, out, M_, C_, C_);
}